// Round 10
// baseline (251.433 us; speedup 1.0000x reference)
//
#include <hip/hip_runtime.h>

typedef unsigned long long u64;

#define CH 256   // cols (boxes) per scan chunk
#define CW 4     // 64-bit words per chunk
#define TW 8     // tile words held per row (this chunk + next chunk)
#define TP 9     // padded row length (72B rows -> 4-way LDS conflict, not 16)

// ---------------- K1a: partial rank counts (no atomics) ----------------
__global__ __launch_bounds__(256)
void k_rank_part(const float* __restrict__ preds, int n, int cpb,
                 int* __restrict__ pc) {
  __shared__ float cs[1024];
  int c0 = blockIdx.y * cpb;
  int cn = min(cpb, n - c0);
  for (int j = threadIdx.x; j < cn; j += blockDim.x)
    cs[j] = preds[(c0 + j) * 5 + 4];
  __syncthreads();
  int i = blockIdx.x * blockDim.x + threadIdx.x;
  if (i >= n) return;
  float ci = preds[i * 5 + 4];
  int cnt = 0;
  const float4* cs4 = (const float4*)cs;
  int cn4 = cn >> 2;
  for (int j4 = 0; j4 < cn4; ++j4) {
    float4 c4 = cs4[j4];
    int jb = c0 + j4 * 4;
    cnt += (c4.x > ci) || (c4.x == ci && (jb + 0) < i);
    cnt += (c4.y > ci) || (c4.y == ci && (jb + 1) < i);
    cnt += (c4.z > ci) || (c4.z == ci && (jb + 2) < i);
    cnt += (c4.w > ci) || (c4.w == ci && (jb + 3) < i);
  }
  for (int j = cn4 * 4; j < cn; ++j)
    cnt += (cs[j] > ci) || (cs[j] == ci && (c0 + j) < i);
  pc[(size_t)blockIdx.y * n + i] = cnt;
}

// ---------------- K1b: sum partials + scatter ----------------
__global__ __launch_bounds__(256)
void k_scatter(const float* __restrict__ preds, const int* __restrict__ pc,
               int n, int nyb, float* __restrict__ sboxes,
               int* __restrict__ sidx) {
  int i = blockIdx.x * blockDim.x + threadIdx.x;
  if (i >= n) return;
  int pos = 0;
  for (int y = 0; y < nyb; ++y) pos += pc[(size_t)y * n + i];
  sboxes[pos * 4 + 0] = preds[i * 5 + 0];
  sboxes[pos * 4 + 1] = preds[i * 5 + 1];
  sboxes[pos * 4 + 2] = preds[i * 5 + 2];
  sboxes[pos * 4 + 3] = preds[i * 5 + 3];
  sidx[pos] = i;
}

// ---------------- K2: suppression bitmask, row-major ----------------
// M[row*nw + w] : bit j = IoU(row, col=w*64+j) > thresh && col > row
// Only w >= row/64 is valid; sub-diagonal words are garbage but only ever
// AND into already-drained scan words (provably harmless).
__global__ void k_mask(const float* __restrict__ sboxes, int n,
                       const float* __restrict__ thr_p,
                       u64* __restrict__ M, int nw) {
  int wx = blockIdx.x;  // column word
  int ry = blockIdx.y;  // row group
  if (wx < ry) return;
  int lane = threadIdx.x;

  __shared__ float4 cb[64];
  __shared__ float cbar[64];
  const float4* sb4 = (const float4*)sboxes;
  int col0 = wx * 64;
  int cj = col0 + lane;
  int cjc = cj < n ? cj : n - 1;
  {
    float4 b4 = sb4[cjc];
    cb[lane] = b4;
    cbar[lane] = __fmul_rn(__fsub_rn(b4.z, b4.x), __fsub_rn(b4.w, b4.y));
  }
  __syncthreads();

  int row = ry * 64 + lane;
  if (row >= n) return;
  float th = *thr_p;
  float4 r4 = sb4[row];
  float rarea = __fmul_rn(__fsub_rn(r4.z, r4.x), __fsub_rn(r4.w, r4.y));

  u64 w = 0;
#pragma unroll 8
  for (int j = 0; j < 64; ++j) {
    float4 c4 = cb[j];
    float ix1 = fmaxf(r4.x, c4.x);
    float iy1 = fmaxf(r4.y, c4.y);
    float ix2 = fminf(r4.z, c4.z);
    float iy2 = fminf(r4.w, c4.w);
    float iw = fmaxf(__fsub_rn(ix2, ix1), 0.0f);
    float ih = fmaxf(__fsub_rn(iy2, iy1), 0.0f);
    float inter = __fmul_rn(iw, ih);
    float denom = __fadd_rn(__fsub_rn(__fadd_rn(rarea, cbar[j]), inter), 1e-12f);
    float iou = __fdiv_rn(inter, denom);
    int col = col0 + j;
    bool sup = (col > row) && (col < n) && (iou > th);
    w |= ((u64)sup) << j;
  }
  M[(size_t)row * nw + wx] = w;
}

// keep a 64-bit value resident in VGPRs (opaque def: no LDS rematerialization)
#define PIN(x) asm volatile("" : "+v"(x))

// wave-uniform 64-bit broadcast from lane bs (uniform) via v_readlane
__device__ __forceinline__ u64 bcast64(u64 v, int bs) {
  unsigned lo = __builtin_amdgcn_readlane((unsigned)v, bs);
  unsigned hi = __builtin_amdgcn_readlane((unsigned)(v >> 32), bs);
  return ((u64)hi << 32) | lo;
}

// force a wave-uniform 64-bit value into scalar registers
__device__ __forceinline__ u64 sgpr64(u64 v) {
  unsigned lo = __builtin_amdgcn_readfirstlane((unsigned)v);
  unsigned hi = __builtin_amdgcn_readfirstlane((unsigned)(v >> 32));
  return ((u64)hi << 32) | lo;
}

// lane's 8 tile words for rows (OFS+lane) of the current chunk
#define LOADW(R, OFS)                                                        \
  u64 d##R##0 = dbuf[cbuf][(OFS) + lane][0],                                 \
      d##R##1 = dbuf[cbuf][(OFS) + lane][1],                                 \
      d##R##2 = dbuf[cbuf][(OFS) + lane][2],                                 \
      d##R##3 = dbuf[cbuf][(OFS) + lane][3],                                 \
      d##R##4 = dbuf[cbuf][(OFS) + lane][4],                                 \
      d##R##5 = dbuf[cbuf][(OFS) + lane][5],                                 \
      d##R##6 = dbuf[cbuf][(OFS) + lane][6],                                 \
      d##R##7 = dbuf[cbuf][(OFS) + lane][7];                                 \
  PIN(d##R##0); PIN(d##R##1); PIN(d##R##2); PIN(d##R##3);                    \
  PIN(d##R##4); PIN(d##R##5); PIN(d##R##6); PIN(d##R##7);

// serial greedy scan of word Q; broadcasts 8 words: 4 into rem (chain),
// 4 into nx carry for the next chunk (off-chain).
#define SCAN_WORD(Q)                                                         \
  if (!stop)                                                                 \
    while (rem##Q) {                                                         \
      int b = (int)__builtin_ctzll(rem##Q);                                  \
      kept##Q |= (u64)1 << b;                                                \
      ++out;                                                                 \
      if (out >= maxp) { stop = true; break; }                               \
      u64 s0 = bcast64(d##Q##0, b), s1 = bcast64(d##Q##1, b),                \
          s2 = bcast64(d##Q##2, b), s3 = bcast64(d##Q##3, b);                \
      u64 s4 = bcast64(d##Q##4, b), s5 = bcast64(d##Q##5, b),                \
          s6 = bcast64(d##Q##6, b), s7 = bcast64(d##Q##7, b);                \
      rem##Q &= rem##Q - 1;                                                  \
      rem0 &= ~s0; rem1 &= ~s1; rem2 &= ~s2; rem3 &= ~s3;                    \
      nx0 &= ~s4; nx1 &= ~s5; nx2 &= ~s6; nx3 &= ~s7;                        \
    }

// dump kept positions of word Q: lane handles bit 'lane'
#define DUMP_WORD(Q, BASE)                                                   \
  if (kept##Q & lbit) {                                                      \
    int r = (BASE) + (int)__popcll(kept##Q & lmask);                         \
    int p = c * CH + (Q) * 64 + lane;                                        \
    plist[cbuf][r] = p;                                                      \
    int o = out0 + r;                                                        \
    if (o < maxp) sel[o] = p;                                                \
  }

// ---------------- K3: pipelined chunked greedy scan (1 WG, 8 waves) ----------------
// Per chunk (ONE barrier): wave 0 scans chunk c purely from registers
// (rem = live & carry; carry covers picks of c-1 via the 8-word tile);
// waves 1-3 apply picks(c-1) to live[words >= (c+2)*CW] (coalesced, hidden);
// waves 4-7 prefetch the 8-word tile of chunk c+1.
__global__ __launch_bounds__(512, 1)
void k_scan(const u64* __restrict__ M, int n, int nw, int maxp,
            int* __restrict__ sel, int* __restrict__ cnt) {
  __shared__ u64 live[128];
  __shared__ u64 dbuf[2][CH][TP];
  __shared__ int plist[2][CH];
  __shared__ int pcnt[2];
  __shared__ int done_s;
  int t = threadIdx.x;           // 0..511
  int wave = t >> 6;
  int lane = t & 63;
  int nch = (nw + CW - 1) / CW;

  if (t < 128) {
    u64 v = ~0ULL;
    int base = t * 64;
    if (t >= nw || base >= n) v = 0ULL;
    else if (base + 64 > n) v = (1ULL << (n - base)) - 1ULL;
    live[t] = v;
  }
  if (t == 0) { pcnt[0] = 0; pcnt[1] = 0; done_s = 0; }
  if (t < CH) {   // prologue: 8-word tile of chunk 0
    const u64* src = M + (size_t)t * nw;
#pragma unroll
    for (int q = 0; q < TW; ++q)
      dbuf[0][t][q] = (t < n && q < nw) ? src[q] : 0ULL;
  }
  __syncthreads();

  int out = 0;
  u64 ca0 = ~0ULL, ca1 = ~0ULL, ca2 = ~0ULL, ca3 = ~0ULL;  // carry (wave 0)

  for (int c = 0; c < nch; ++c) {
    int cbuf = c & 1;

    if (wave == 0) {
      // tile -> 32 pinned u64 registers (rows lane, 64+lane, 128+lane, 192+lane)
      LOADW(0, 0)
      LOADW(1, 64)
      LOADW(2, 128)
      LOADW(3, 192)

      // rem = live (picks <= c-2) & carry (picks of c-1); pure SGPR state
      u64 rem0 = sgpr64((c * CW + 0 < nw) ? live[c * CW + 0] : 0ULL) & ca0;
      u64 rem1 = sgpr64((c * CW + 1 < nw) ? live[c * CW + 1] : 0ULL) & ca1;
      u64 rem2 = sgpr64((c * CW + 2 < nw) ? live[c * CW + 2] : 0ULL) & ca2;
      u64 rem3 = sgpr64((c * CW + 3 < nw) ? live[c * CW + 3] : 0ULL) & ca3;
      u64 nx0 = ~0ULL, nx1 = ~0ULL, nx2 = ~0ULL, nx3 = ~0ULL;

      u64 kept0 = 0, kept1 = 0, kept2 = 0, kept3 = 0;
      int out0 = out;
      bool stop = false;

      SCAN_WORD(0)
      SCAN_WORD(1)
      SCAN_WORD(2)
      SCAN_WORD(3)

      ca0 = nx0; ca1 = nx1; ca2 = nx2; ca3 = nx3;
      int kc = out - out0;

      {
        int b1 = (int)__popcll(kept0);
        int b2 = b1 + (int)__popcll(kept1);
        int b3 = b2 + (int)__popcll(kept2);
        u64 lbit = (u64)1 << lane;
        u64 lmask = lbit - 1;
        DUMP_WORD(0, 0)
        DUMP_WORD(1, b1)
        DUMP_WORD(2, b2)
        DUMP_WORD(3, b3)
      }
      if (lane == 0) {
        pcnt[cbuf] = kc;
        if (stop) done_s = 1;
      }
    } else if (wave < 4) {
      // apply picks of chunk c-1 to live[w] for w >= (c+2)*CW (carry covers
      // words of chunk c+1... no: carry covers chunk c; waves cover >= c+2
      // is wrong by one? carry computed during chunk c-1 covers words of c.
      // So waves must cover words >= (c+1)*CW. Those are read earliest at
      // chunk c+1 by wave 0 -> must land before end-of-chunk barrier. OK.)
      int pb = (c - 1) & 1;
      int pcn = (c > 0) ? pcnt[pb] : 0;
      int tid2 = t - 64;                 // 0..191
      int w = (c + 1) * CW + tid2;
      if (pcn > 0 && w < nw) {
        u64 acc = 0;
        for (int i0 = 0; i0 < pcn; i0 += 8) {
          int lim = pcn - 1;
          int j1 = i0 + 1, j2 = i0 + 2, j3 = i0 + 3;
          int j4 = i0 + 4, j5 = i0 + 5, j6 = i0 + 6, j7 = i0 + 7;
          int r0 = plist[pb][i0];
          int r1 = plist[pb][j1 < pcn ? j1 : lim];
          int r2 = plist[pb][j2 < pcn ? j2 : lim];
          int r3 = plist[pb][j3 < pcn ? j3 : lim];
          int r4 = plist[pb][j4 < pcn ? j4 : lim];
          int r5 = plist[pb][j5 < pcn ? j5 : lim];
          int r6 = plist[pb][j6 < pcn ? j6 : lim];
          int r7 = plist[pb][j7 < pcn ? j7 : lim];
          u64 v0 = M[(size_t)r0 * nw + w];
          u64 v1 = M[(size_t)r1 * nw + w];
          u64 v2 = M[(size_t)r2 * nw + w];
          u64 v3 = M[(size_t)r3 * nw + w];
          u64 v4 = M[(size_t)r4 * nw + w];
          u64 v5 = M[(size_t)r5 * nw + w];
          u64 v6 = M[(size_t)r6 * nw + w];
          u64 v7 = M[(size_t)r7 * nw + w];
          acc |= v0;
          acc |= (j1 < pcn) ? v1 : 0ULL;
          acc |= (j2 < pcn) ? v2 : 0ULL;
          acc |= (j3 < pcn) ? v3 : 0ULL;
          acc |= (j4 < pcn) ? v4 : 0ULL;
          acc |= (j5 < pcn) ? v5 : 0ULL;
          acc |= (j6 < pcn) ? v6 : 0ULL;
          acc |= (j7 < pcn) ? v7 : 0ULL;
        }
        live[w] &= ~acc;   // single writer per word
      }
    } else {
      // prefetch 8-word tile of chunk c+1
      int c1 = c + 1;
      if (c1 < nch) {
        int rl = t - 256;                // 0..255
        int r = c1 * CH + rl;
        const u64* src = M + (size_t)r * nw + c1 * CW;
#pragma unroll
        for (int q = 0; q < TW; ++q) {
          int w = c1 * CW + q;
          dbuf[c1 & 1][rl][q] = (r < n && w < nw) ? src[q] : 0ULL;
        }
      }
    }
    __syncthreads();
    if (done_s) break;
  }
  if (t == 0) *cnt = (out < maxp) ? out : maxp;
}

// ---------------- K4: gather outputs ----------------
__global__ void k_emit(const float* __restrict__ preds,
                       const int* __restrict__ sidx,
                       const int* __restrict__ sel,
                       const int* __restrict__ cnt,
                       int maxp, float* __restrict__ out) {
  int k = blockIdx.x * blockDim.x + threadIdx.x;
  if (k >= maxp) return;
  int nk = *cnt;
  if (k < nk) {
    int p = sel[k];
    int orig = sidx[p];
#pragma unroll
    for (int q = 0; q < 5; ++q) out[k * 5 + q] = preds[orig * 5 + q];
    out[(size_t)maxp * 5 + k] = (float)orig;
  } else {
#pragma unroll
    for (int q = 0; q < 5; ++q) out[k * 5 + q] = 0.0f;
    out[(size_t)maxp * 5 + k] = -1.0f;
  }
}

extern "C" void kernel_launch(void* const* d_in, const int* in_sizes, int n_in,
                              void* d_out, int out_size, void* d_ws, size_t ws_size,
                              hipStream_t stream) {
  const float* preds = (const float*)d_in[0];
  const float* thr   = (const float*)d_in[1];
  float* out = (float*)d_out;
  int n    = in_sizes[0] / 5;          // 8192
  int maxp = out_size / 6;             // 1000
  int nw   = (n + 63) / 64;            // 128
  int cpb  = 1024;
  int nyb  = (n + cpb - 1) / cpb;      // 8

  char* ws = (char*)d_ws;
  u64* M = (u64*)ws;
  size_t off = (size_t)n * nw * sizeof(u64);                 // 8 MB
  float* sboxes = (float*)(ws + off);  off += (size_t)n * 4 * sizeof(float);
  int*   sidx   = (int*)(ws + off);    off += (size_t)n * sizeof(int);
  int*   sel    = (int*)(ws + off);    off += (size_t)maxp * sizeof(int);
  int*   cnt    = (int*)(ws + off);    off += sizeof(int) * 4;
  int*   pc     = (int*)(ws + off);    // nyb * n ints

  hipLaunchKernelGGL(k_rank_part, dim3((n + 255) / 256, nyb), dim3(256), 0,
                     stream, preds, n, cpb, pc);
  hipLaunchKernelGGL(k_scatter, dim3((n + 255) / 256), dim3(256), 0, stream,
                     preds, pc, n, nyb, sboxes, sidx);
  hipLaunchKernelGGL(k_mask, dim3(nw, nw), dim3(64), 0, stream,
                     sboxes, n, thr, M, nw);
  hipLaunchKernelGGL(k_scan, dim3(1), dim3(512), 0, stream,
                     M, n, nw, maxp, sel, cnt);
  hipLaunchKernelGGL(k_emit, dim3((maxp + 255) / 256), dim3(256), 0, stream,
                     preds, sidx, sel, cnt, maxp, out);
}

// Round 11
// 248.122 us; speedup vs baseline: 1.0133x; 1.0133x over previous
//
#include <hip/hip_runtime.h>

typedef unsigned long long u64;

#define CH 256   // cols (boxes) per scan chunk
#define CW 4     // 64-bit words per chunk
#define TW 8     // tile words held per row (this chunk + next chunk)
#define TP 9     // padded LDS row (72B -> 2-way bank conflict only)

// ---------------- K1a: partial rank counts (no atomics) ----------------
__global__ __launch_bounds__(256)
void k_rank_part(const float* __restrict__ preds, int n, int cpb,
                 int* __restrict__ pc) {
  __shared__ float cs[1024];
  int c0 = blockIdx.y * cpb;
  int cn = min(cpb, n - c0);
  for (int j = threadIdx.x; j < cn; j += blockDim.x)
    cs[j] = preds[(c0 + j) * 5 + 4];
  __syncthreads();
  int i = blockIdx.x * blockDim.x + threadIdx.x;
  if (i >= n) return;
  float ci = preds[i * 5 + 4];
  int cnt = 0;
  const float4* cs4 = (const float4*)cs;
  int cn4 = cn >> 2;
  for (int j4 = 0; j4 < cn4; ++j4) {
    float4 c4 = cs4[j4];
    int jb = c0 + j4 * 4;
    cnt += (c4.x > ci) || (c4.x == ci && (jb + 0) < i);
    cnt += (c4.y > ci) || (c4.y == ci && (jb + 1) < i);
    cnt += (c4.z > ci) || (c4.z == ci && (jb + 2) < i);
    cnt += (c4.w > ci) || (c4.w == ci && (jb + 3) < i);
  }
  for (int j = cn4 * 4; j < cn; ++j)
    cnt += (cs[j] > ci) || (cs[j] == ci && (c0 + j) < i);
  pc[(size_t)blockIdx.y * n + i] = cnt;
}

// ---------------- K1b: sum partials + scatter ----------------
__global__ __launch_bounds__(256)
void k_scatter(const float* __restrict__ preds, const int* __restrict__ pc,
               int n, int nyb, float* __restrict__ sboxes,
               int* __restrict__ sidx) {
  int i = blockIdx.x * blockDim.x + threadIdx.x;
  if (i >= n) return;
  int pos = 0;
  for (int y = 0; y < nyb; ++y) pos += pc[(size_t)y * n + i];
  sboxes[pos * 4 + 0] = preds[i * 5 + 0];
  sboxes[pos * 4 + 1] = preds[i * 5 + 1];
  sboxes[pos * 4 + 2] = preds[i * 5 + 2];
  sboxes[pos * 4 + 3] = preds[i * 5 + 3];
  sidx[pos] = i;
}

// ---------------- K2: suppression bitmask ----------------
// M[row*nw + w] (row-major, for the apply phase) and, for the 8-word diagonal
// band, a CONTIGUOUS copy D[crow][row&255][q] (q = w - crow*CW in [0,8)) so the
// scan's tile prefetch is a sequential 16KB stream.
__global__ void k_mask(const float* __restrict__ sboxes, int n,
                       const float* __restrict__ thr_p,
                       u64* __restrict__ M, u64* __restrict__ D, int nw) {
  int wx = blockIdx.x;  // column word
  int ry = blockIdx.y;  // row group
  if (wx < ry) return;
  int lane = threadIdx.x;

  __shared__ float4 cb[64];
  __shared__ float cbar[64];
  const float4* sb4 = (const float4*)sboxes;
  int col0 = wx * 64;
  int cj = col0 + lane;
  int cjc = cj < n ? cj : n - 1;
  {
    float4 b4 = sb4[cjc];
    cb[lane] = b4;
    cbar[lane] = __fmul_rn(__fsub_rn(b4.z, b4.x), __fsub_rn(b4.w, b4.y));
  }
  __syncthreads();

  int row = ry * 64 + lane;
  if (row >= n) return;
  float th = *thr_p;
  float4 r4 = sb4[row];
  float rarea = __fmul_rn(__fsub_rn(r4.z, r4.x), __fsub_rn(r4.w, r4.y));

  u64 w = 0;
#pragma unroll 8
  for (int j = 0; j < 64; ++j) {
    float4 c4 = cb[j];
    float ix1 = fmaxf(r4.x, c4.x);
    float iy1 = fmaxf(r4.y, c4.y);
    float ix2 = fminf(r4.z, c4.z);
    float iy2 = fminf(r4.w, c4.w);
    float iw = fmaxf(__fsub_rn(ix2, ix1), 0.0f);
    float ih = fmaxf(__fsub_rn(iy2, iy1), 0.0f);
    float inter = __fmul_rn(iw, ih);
    float denom = __fadd_rn(__fsub_rn(__fadd_rn(rarea, cbar[j]), inter), 1e-12f);
    float iou = __fdiv_rn(inter, denom);
    int col = col0 + j;
    bool sup = (col > row) && (col < n) && (iou > th);
    w |= ((u64)sup) << j;
  }
  M[(size_t)row * nw + wx] = w;
  int crow = row >> 8;                 // row's chunk
  int q = wx - crow * CW;              // wave-uniform
  if (q >= 0 && q < TW)
    D[((size_t)crow * CH + (row & (CH - 1))) * TW + q] = w;
}

// keep a 64-bit value resident in VGPRs (opaque def: no LDS rematerialization)
#define PIN(x) asm volatile("" : "+v"(x))

// wave-uniform 64-bit broadcast from lane bs (uniform) via v_readlane
__device__ __forceinline__ u64 bcast64(u64 v, int bs) {
  unsigned lo = __builtin_amdgcn_readlane((unsigned)v, bs);
  unsigned hi = __builtin_amdgcn_readlane((unsigned)(v >> 32), bs);
  return ((u64)hi << 32) | lo;
}

// force a wave-uniform 64-bit value into scalar registers
__device__ __forceinline__ u64 sgpr64(u64 v) {
  unsigned lo = __builtin_amdgcn_readfirstlane((unsigned)v);
  unsigned hi = __builtin_amdgcn_readfirstlane((unsigned)(v >> 32));
  return ((u64)hi << 32) | lo;
}

// lane's 8 tile words for rows (OFS+lane) of the current chunk
#define LOADW(R, OFS)                                                        \
  u64 d##R##0 = dbuf[cbuf][(OFS) + lane][0],                                 \
      d##R##1 = dbuf[cbuf][(OFS) + lane][1],                                 \
      d##R##2 = dbuf[cbuf][(OFS) + lane][2],                                 \
      d##R##3 = dbuf[cbuf][(OFS) + lane][3],                                 \
      d##R##4 = dbuf[cbuf][(OFS) + lane][4],                                 \
      d##R##5 = dbuf[cbuf][(OFS) + lane][5],                                 \
      d##R##6 = dbuf[cbuf][(OFS) + lane][6],                                 \
      d##R##7 = dbuf[cbuf][(OFS) + lane][7];                                 \
  PIN(d##R##0); PIN(d##R##1); PIN(d##R##2); PIN(d##R##3);                    \
  PIN(d##R##4); PIN(d##R##5); PIN(d##R##6); PIN(d##R##7);

// serial greedy scan of word Q; broadcasts 8 words: 4 into rem (chain),
// 4 into nx carry for the next chunk (off-chain).
#define SCAN_WORD(Q)                                                         \
  if (!stop)                                                                 \
    while (rem##Q) {                                                         \
      int b = (int)__builtin_ctzll(rem##Q);                                  \
      kept##Q |= (u64)1 << b;                                                \
      ++out;                                                                 \
      if (out >= maxp) { stop = true; break; }                               \
      u64 s0 = bcast64(d##Q##0, b), s1 = bcast64(d##Q##1, b),                \
          s2 = bcast64(d##Q##2, b), s3 = bcast64(d##Q##3, b);                \
      u64 s4 = bcast64(d##Q##4, b), s5 = bcast64(d##Q##5, b),                \
          s6 = bcast64(d##Q##6, b), s7 = bcast64(d##Q##7, b);                \
      rem##Q &= rem##Q - 1;                                                  \
      rem0 &= ~s0; rem1 &= ~s1; rem2 &= ~s2; rem3 &= ~s3;                    \
      nx0 &= ~s4; nx1 &= ~s5; nx2 &= ~s6; nx3 &= ~s7;                        \
    }

// dump kept positions of word Q: lane handles bit 'lane'
#define DUMP_WORD(Q, BASE)                                                   \
  if (kept##Q & lbit) {                                                      \
    int r = (BASE) + (int)__popcll(kept##Q & lmask);                         \
    int p = c * CH + (Q) * 64 + lane;                                        \
    plist[cbuf][r] = p;                                                      \
    int o = out0 + r;                                                        \
    if (o < maxp) sel[o] = p;                                                \
  }

// 16-deep unconditional-clamped apply batch (16 loads in flight per thread)
#define APPLY16(OFS)                                                         \
  {                                                                          \
    int lim = pcn - 1;                                                       \
    int k0 = (OFS);                                                          \
    int a0 = k0, a1 = k0 + 1, a2 = k0 + 2, a3 = k0 + 3, a4 = k0 + 4,         \
        a5 = k0 + 5, a6 = k0 + 6, a7 = k0 + 7, a8 = k0 + 8, a9 = k0 + 9,     \
        aA = k0 + 10, aB = k0 + 11, aC = k0 + 12, aD = k0 + 13,              \
        aE = k0 + 14, aF = k0 + 15;                                          \
    int r0 = plist[pb][a0 < pcn ? a0 : lim];                                 \
    int r1 = plist[pb][a1 < pcn ? a1 : lim];                                 \
    int r2 = plist[pb][a2 < pcn ? a2 : lim];                                 \
    int r3 = plist[pb][a3 < pcn ? a3 : lim];                                 \
    int r4 = plist[pb][a4 < pcn ? a4 : lim];                                 \
    int r5 = plist[pb][a5 < pcn ? a5 : lim];                                 \
    int r6 = plist[pb][a6 < pcn ? a6 : lim];                                 \
    int r7 = plist[pb][a7 < pcn ? a7 : lim];                                 \
    int r8 = plist[pb][a8 < pcn ? a8 : lim];                                 \
    int r9 = plist[pb][a9 < pcn ? a9 : lim];                                 \
    int rA = plist[pb][aA < pcn ? aA : lim];                                 \
    int rB = plist[pb][aB < pcn ? aB : lim];                                 \
    int rC = plist[pb][aC < pcn ? aC : lim];                                 \
    int rD = plist[pb][aD < pcn ? aD : lim];                                 \
    int rE = plist[pb][aE < pcn ? aE : lim];                                 \
    int rF = plist[pb][aF < pcn ? aF : lim];                                 \
    u64 v0 = M[(size_t)r0 * nw + w], v1 = M[(size_t)r1 * nw + w];            \
    u64 v2 = M[(size_t)r2 * nw + w], v3 = M[(size_t)r3 * nw + w];            \
    u64 v4 = M[(size_t)r4 * nw + w], v5 = M[(size_t)r5 * nw + w];            \
    u64 v6 = M[(size_t)r6 * nw + w], v7 = M[(size_t)r7 * nw + w];            \
    u64 v8 = M[(size_t)r8 * nw + w], v9 = M[(size_t)r9 * nw + w];            \
    u64 vA = M[(size_t)rA * nw + w], vB = M[(size_t)rB * nw + w];            \
    u64 vC = M[(size_t)rC * nw + w], vD = M[(size_t)rD * nw + w];            \
    u64 vE = M[(size_t)rE * nw + w], vF = M[(size_t)rF * nw + w];            \
    acc |= v0;                                                               \
    acc |= (a1 < pcn) ? v1 : 0ULL;  acc |= (a2 < pcn) ? v2 : 0ULL;           \
    acc |= (a3 < pcn) ? v3 : 0ULL;  acc |= (a4 < pcn) ? v4 : 0ULL;           \
    acc |= (a5 < pcn) ? v5 : 0ULL;  acc |= (a6 < pcn) ? v6 : 0ULL;           \
    acc |= (a7 < pcn) ? v7 : 0ULL;  acc |= (a8 < pcn) ? v8 : 0ULL;           \
    acc |= (a9 < pcn) ? v9 : 0ULL;  acc |= (aA < pcn) ? vA : 0ULL;           \
    acc |= (aB < pcn) ? vB : 0ULL;  acc |= (aC < pcn) ? vC : 0ULL;           \
    acc |= (aD < pcn) ? vD : 0ULL;  acc |= (aE < pcn) ? vE : 0ULL;           \
    acc |= (aF < pcn) ? vF : 0ULL;                                           \
  }

// ---------------- K3: pipelined chunked greedy scan (1 WG, 8 waves) ----------------
// Per chunk (ONE barrier): wave 0 scans chunk c purely from registers
// (rem = live & carry; carry holds picks(c-1)'s effect on chunk c);
// waves 1-3 apply picks(c-1) to live[w >= (c+1)*CW] (coalesced rows of M);
// waves 4-7 prefetch chunk c+1's 8-word tile from the CONTIGUOUS band D.
__global__ __launch_bounds__(512, 1)
void k_scan(const u64* __restrict__ M, const u64* __restrict__ D,
            int n, int nw, int maxp,
            int* __restrict__ sel, int* __restrict__ cnt) {
  __shared__ u64 live[128];
  __shared__ u64 dbuf[2][CH][TP];
  __shared__ int plist[2][CH];
  __shared__ int pcnt[2];
  __shared__ int done_s;
  int t = threadIdx.x;           // 0..511
  int wave = t >> 6;
  int lane = t & 63;
  int nch = (nw + CW - 1) / CW;

  if (t < 128) {
    u64 v = ~0ULL;
    int base = t * 64;
    if (t >= nw || base >= n) v = 0ULL;
    else if (base + 64 > n) v = (1ULL << (n - base)) - 1ULL;
    live[t] = v;
  }
  if (t == 0) { pcnt[0] = 0; pcnt[1] = 0; done_s = 0; }
  if (t < CH) {   // prologue: chunk-0 tile from D (contiguous)
    const u64* src = D + (size_t)t * TW;
    u64 v0 = src[0], v1 = src[1], v2 = src[2], v3 = src[3];
    u64 v4 = src[4], v5 = src[5], v6 = src[6], v7 = src[7];
    bool rok = t < n;
    dbuf[0][t][0] = (rok && 0 < nw) ? v0 : 0ULL;
    dbuf[0][t][1] = (rok && 1 < nw) ? v1 : 0ULL;
    dbuf[0][t][2] = (rok && 2 < nw) ? v2 : 0ULL;
    dbuf[0][t][3] = (rok && 3 < nw) ? v3 : 0ULL;
    dbuf[0][t][4] = (rok && 4 < nw) ? v4 : 0ULL;
    dbuf[0][t][5] = (rok && 5 < nw) ? v5 : 0ULL;
    dbuf[0][t][6] = (rok && 6 < nw) ? v6 : 0ULL;
    dbuf[0][t][7] = (rok && 7 < nw) ? v7 : 0ULL;
  }
  __syncthreads();

  int out = 0;
  u64 ca0 = ~0ULL, ca1 = ~0ULL, ca2 = ~0ULL, ca3 = ~0ULL;  // carry (wave 0)

  for (int c = 0; c < nch; ++c) {
    int cbuf = c & 1;

    if (wave == 0) {
      // tile -> 32 pinned u64 registers (rows lane, 64+lane, 128+lane, 192+lane)
      LOADW(0, 0)
      LOADW(1, 64)
      LOADW(2, 128)
      LOADW(3, 192)

      // rem = live (picks <= c-2) & carry (picks of c-1); uniform SGPR state
      u64 rem0 = sgpr64((c * CW + 0 < nw) ? live[c * CW + 0] : 0ULL) & ca0;
      u64 rem1 = sgpr64((c * CW + 1 < nw) ? live[c * CW + 1] : 0ULL) & ca1;
      u64 rem2 = sgpr64((c * CW + 2 < nw) ? live[c * CW + 2] : 0ULL) & ca2;
      u64 rem3 = sgpr64((c * CW + 3 < nw) ? live[c * CW + 3] : 0ULL) & ca3;
      u64 nx0 = ~0ULL, nx1 = ~0ULL, nx2 = ~0ULL, nx3 = ~0ULL;

      u64 kept0 = 0, kept1 = 0, kept2 = 0, kept3 = 0;
      int out0 = out;
      bool stop = false;

      SCAN_WORD(0)
      SCAN_WORD(1)
      SCAN_WORD(2)
      SCAN_WORD(3)

      ca0 = nx0; ca1 = nx1; ca2 = nx2; ca3 = nx3;
      int kc = out - out0;

      {
        int b1 = (int)__popcll(kept0);
        int b2 = b1 + (int)__popcll(kept1);
        int b3 = b2 + (int)__popcll(kept2);
        u64 lbit = (u64)1 << lane;
        u64 lmask = lbit - 1;
        DUMP_WORD(0, 0)
        DUMP_WORD(1, b1)
        DUMP_WORD(2, b2)
        DUMP_WORD(3, b3)
      }
      if (lane == 0) {
        pcnt[cbuf] = kc;
        if (stop) done_s = 1;
      }
    } else if (wave < 4) {
      // apply picks(c-1) to live[w] for all w >= (c+1)*CW; the 4-word gap
      // (chunk c+1's own words) is covered by wave 0's carry.
      int pb = (c - 1) & 1;
      int pcn = (c > 0) ? pcnt[pb] : 0;
      int tid2 = t - 64;                 // 0..191
      int w = (c + 1) * CW + tid2;
      if (pcn > 0 && w < nw) {
        u64 acc = 0;
        for (int i0 = 0; i0 < pcn; i0 += 16) APPLY16(i0)
        live[w] &= ~acc;   // single writer per word
      }
    } else {
      // prefetch chunk c+1's tile from D: sequential 16KB, 64B per thread
      int c1 = c + 1;
      if (c1 < nch) {
        int rl = t - 256;                // 0..255
        const u64* src = D + ((size_t)c1 * CH + rl) * TW;
        u64 v0 = src[0], v1 = src[1], v2 = src[2], v3 = src[3];
        u64 v4 = src[4], v5 = src[5], v6 = src[6], v7 = src[7];
        bool rok = (c1 * CH + rl) < n;
        int wb = c1 * CW;
        dbuf[c1 & 1][rl][0] = (rok && wb + 0 < nw) ? v0 : 0ULL;
        dbuf[c1 & 1][rl][1] = (rok && wb + 1 < nw) ? v1 : 0ULL;
        dbuf[c1 & 1][rl][2] = (rok && wb + 2 < nw) ? v2 : 0ULL;
        dbuf[c1 & 1][rl][3] = (rok && wb + 3 < nw) ? v3 : 0ULL;
        dbuf[c1 & 1][rl][4] = (rok && wb + 4 < nw) ? v4 : 0ULL;
        dbuf[c1 & 1][rl][5] = (rok && wb + 5 < nw) ? v5 : 0ULL;
        dbuf[c1 & 1][rl][6] = (rok && wb + 6 < nw) ? v6 : 0ULL;
        dbuf[c1 & 1][rl][7] = (rok && wb + 7 < nw) ? v7 : 0ULL;
      }
    }
    __syncthreads();
    if (done_s) break;
  }
  if (t == 0) *cnt = (out < maxp) ? out : maxp;
}

// ---------------- K4: gather outputs ----------------
__global__ void k_emit(const float* __restrict__ preds,
                       const int* __restrict__ sidx,
                       const int* __restrict__ sel,
                       const int* __restrict__ cnt,
                       int maxp, float* __restrict__ out) {
  int k = blockIdx.x * blockDim.x + threadIdx.x;
  if (k >= maxp) return;
  int nk = *cnt;
  if (k < nk) {
    int p = sel[k];
    int orig = sidx[p];
#pragma unroll
    for (int q = 0; q < 5; ++q) out[k * 5 + q] = preds[orig * 5 + q];
    out[(size_t)maxp * 5 + k] = (float)orig;
  } else {
#pragma unroll
    for (int q = 0; q < 5; ++q) out[k * 5 + q] = 0.0f;
    out[(size_t)maxp * 5 + k] = -1.0f;
  }
}

extern "C" void kernel_launch(void* const* d_in, const int* in_sizes, int n_in,
                              void* d_out, int out_size, void* d_ws, size_t ws_size,
                              hipStream_t stream) {
  const float* preds = (const float*)d_in[0];
  const float* thr   = (const float*)d_in[1];
  float* out = (float*)d_out;
  int n    = in_sizes[0] / 5;          // 8192
  int maxp = out_size / 6;             // 1000
  int nw   = (n + 63) / 64;            // 128
  int nch  = (nw + CW - 1) / CW;       // 32
  int cpb  = 1024;
  int nyb  = (n + cpb - 1) / cpb;      // 8

  char* ws = (char*)d_ws;
  u64* M = (u64*)ws;
  size_t off = (size_t)n * nw * sizeof(u64);                   // 8 MB
  u64* D = (u64*)(ws + off);  off += (size_t)nch * CH * TW * sizeof(u64); // 512 KB
  float* sboxes = (float*)(ws + off);  off += (size_t)n * 4 * sizeof(float);
  int*   sidx   = (int*)(ws + off);    off += (size_t)n * sizeof(int);
  int*   sel    = (int*)(ws + off);    off += (size_t)maxp * sizeof(int);
  int*   cnt    = (int*)(ws + off);    off += sizeof(int) * 4;
  int*   pc     = (int*)(ws + off);    // nyb * n ints

  hipLaunchKernelGGL(k_rank_part, dim3((n + 255) / 256, nyb), dim3(256), 0,
                     stream, preds, n, cpb, pc);
  hipLaunchKernelGGL(k_scatter, dim3((n + 255) / 256), dim3(256), 0, stream,
                     preds, pc, n, nyb, sboxes, sidx);
  hipLaunchKernelGGL(k_mask, dim3(nw, nw), dim3(64), 0, stream,
                     sboxes, n, thr, M, D, nw);
  hipLaunchKernelGGL(k_scan, dim3(1), dim3(512), 0, stream,
                     M, D, n, nw, maxp, sel, cnt);
  hipLaunchKernelGGL(k_emit, dim3((maxp + 255) / 256), dim3(256), 0, stream,
                     preds, sidx, sel, cnt, maxp, out);
}

// Round 12
// 246.434 us; speedup vs baseline: 1.0203x; 1.0068x over previous
//
#include <hip/hip_runtime.h>

typedef unsigned long long u64;

#define CH 512   // cols (boxes) per scan chunk
#define CW 8     // 64-bit words per chunk
#define TP 9     // padded LDS row (72B) to break power-of-2 bank stride

// ---------------- K1a: partial rank counts (no atomics) ----------------
__global__ __launch_bounds__(256)
void k_rank_part(const float* __restrict__ preds, int n, int cpb,
                 int* __restrict__ pc) {
  __shared__ float cs[1024];
  int c0 = blockIdx.y * cpb;
  int cn = min(cpb, n - c0);
  for (int j = threadIdx.x; j < cn; j += blockDim.x)
    cs[j] = preds[(c0 + j) * 5 + 4];
  __syncthreads();
  int i = blockIdx.x * blockDim.x + threadIdx.x;
  if (i >= n) return;
  float ci = preds[i * 5 + 4];
  int cnt = 0;
  const float4* cs4 = (const float4*)cs;
  int cn4 = cn >> 2;
  for (int j4 = 0; j4 < cn4; ++j4) {
    float4 c4 = cs4[j4];
    int jb = c0 + j4 * 4;
    cnt += (c4.x > ci) || (c4.x == ci && (jb + 0) < i);
    cnt += (c4.y > ci) || (c4.y == ci && (jb + 1) < i);
    cnt += (c4.z > ci) || (c4.z == ci && (jb + 2) < i);
    cnt += (c4.w > ci) || (c4.w == ci && (jb + 3) < i);
  }
  for (int j = cn4 * 4; j < cn; ++j)
    cnt += (cs[j] > ci) || (cs[j] == ci && (c0 + j) < i);
  pc[(size_t)blockIdx.y * n + i] = cnt;
}

// ---------------- K1b: sum partials + scatter ----------------
__global__ __launch_bounds__(256)
void k_scatter(const float* __restrict__ preds, const int* __restrict__ pc,
               int n, int nyb, float* __restrict__ sboxes,
               int* __restrict__ sidx) {
  int i = blockIdx.x * blockDim.x + threadIdx.x;
  if (i >= n) return;
  int pos = 0;
  for (int y = 0; y < nyb; ++y) pos += pc[(size_t)y * n + i];
  sboxes[pos * 4 + 0] = preds[i * 5 + 0];
  sboxes[pos * 4 + 1] = preds[i * 5 + 1];
  sboxes[pos * 4 + 2] = preds[i * 5 + 2];
  sboxes[pos * 4 + 3] = preds[i * 5 + 3];
  sidx[pos] = i;
}

// ---------------- K2: suppression bitmask ----------------
// M[row*nw + w] row-major (apply phase) + contiguous diagonal band
// D[crow][row&511][q], q = w - crow*CW in [0,8): the scan tile stream.
__global__ void k_mask(const float* __restrict__ sboxes, int n,
                       const float* __restrict__ thr_p,
                       u64* __restrict__ M, u64* __restrict__ D, int nw) {
  int wx = blockIdx.x;  // column word
  int ry = blockIdx.y;  // row group
  if (wx < ry) return;
  int lane = threadIdx.x;

  __shared__ float4 cb[64];
  __shared__ float cbar[64];
  const float4* sb4 = (const float4*)sboxes;
  int col0 = wx * 64;
  int cj = col0 + lane;
  int cjc = cj < n ? cj : n - 1;
  {
    float4 b4 = sb4[cjc];
    cb[lane] = b4;
    cbar[lane] = __fmul_rn(__fsub_rn(b4.z, b4.x), __fsub_rn(b4.w, b4.y));
  }
  __syncthreads();

  int row = ry * 64 + lane;
  if (row >= n) return;
  float th = *thr_p;
  float4 r4 = sb4[row];
  float rarea = __fmul_rn(__fsub_rn(r4.z, r4.x), __fsub_rn(r4.w, r4.y));

  u64 w = 0;
#pragma unroll 8
  for (int j = 0; j < 64; ++j) {
    float4 c4 = cb[j];
    float ix1 = fmaxf(r4.x, c4.x);
    float iy1 = fmaxf(r4.y, c4.y);
    float ix2 = fminf(r4.z, c4.z);
    float iy2 = fminf(r4.w, c4.w);
    float iw = fmaxf(__fsub_rn(ix2, ix1), 0.0f);
    float ih = fmaxf(__fsub_rn(iy2, iy1), 0.0f);
    float inter = __fmul_rn(iw, ih);
    float denom = __fadd_rn(__fsub_rn(__fadd_rn(rarea, cbar[j]), inter), 1e-12f);
    float iou = __fdiv_rn(inter, denom);
    int col = col0 + j;
    bool sup = (col > row) && (col < n) && (iou > th);
    w |= ((u64)sup) << j;
  }
  M[(size_t)row * nw + wx] = w;
  int crow = row >> 9;                 // row's 512-chunk
  int q = wx - crow * CW;              // wave-uniform
  if (q >= 0 && q < CW)
    D[((size_t)crow * CH + (row & (CH - 1))) * CW + q] = w;
}

// keep a 64-bit value resident in VGPRs (opaque def: no LDS rematerialization)
#define PIN(x) asm volatile("" : "+v"(x))

// wave-uniform 64-bit broadcast from lane bs (uniform) via v_readlane
__device__ __forceinline__ u64 bcast64(u64 v, int bs) {
  unsigned lo = __builtin_amdgcn_readlane((unsigned)v, bs);
  unsigned hi = __builtin_amdgcn_readlane((unsigned)(v >> 32), bs);
  return ((u64)hi << 32) | lo;
}

// force a wave-uniform 64-bit value into scalar registers
__device__ __forceinline__ u64 sgpr64(u64 v) {
  unsigned lo = __builtin_amdgcn_readfirstlane((unsigned)v);
  unsigned hi = __builtin_amdgcn_readfirstlane((unsigned)(v >> 32));
  return ((u64)hi << 32) | lo;
}

// lane's 8 tile words for row Q*64+lane of the current chunk
#define LOADW(Q)                                                             \
  u64 d##Q##0 = dbuf[cbuf][(Q) * 64 + lane][0],                              \
      d##Q##1 = dbuf[cbuf][(Q) * 64 + lane][1],                              \
      d##Q##2 = dbuf[cbuf][(Q) * 64 + lane][2],                              \
      d##Q##3 = dbuf[cbuf][(Q) * 64 + lane][3],                              \
      d##Q##4 = dbuf[cbuf][(Q) * 64 + lane][4],                              \
      d##Q##5 = dbuf[cbuf][(Q) * 64 + lane][5],                              \
      d##Q##6 = dbuf[cbuf][(Q) * 64 + lane][6],                              \
      d##Q##7 = dbuf[cbuf][(Q) * 64 + lane][7];                              \
  PIN(d##Q##0); PIN(d##Q##1); PIN(d##Q##2); PIN(d##Q##3);                    \
  PIN(d##Q##4); PIN(d##Q##5); PIN(d##Q##6); PIN(d##Q##7);

// serial greedy scan of word Q; uniform SGPR chain, no memory ops.
#define SCAN_WORD(Q)                                                         \
  if (!stop)                                                                 \
    while (rem##Q) {                                                         \
      int b = (int)__builtin_ctzll(rem##Q);                                  \
      kept##Q |= (u64)1 << b;                                                \
      ++out;                                                                 \
      if (out >= maxp) { stop = true; break; }                               \
      u64 s0 = bcast64(d##Q##0, b), s1 = bcast64(d##Q##1, b),                \
          s2 = bcast64(d##Q##2, b), s3 = bcast64(d##Q##3, b),                \
          s4 = bcast64(d##Q##4, b), s5 = bcast64(d##Q##5, b),                \
          s6 = bcast64(d##Q##6, b), s7 = bcast64(d##Q##7, b);                \
      rem##Q &= rem##Q - 1;                                                  \
      rem0 &= ~s0; rem1 &= ~s1; rem2 &= ~s2; rem3 &= ~s3;                    \
      rem4 &= ~s4; rem5 &= ~s5; rem6 &= ~s6; rem7 &= ~s7;                    \
    }

// dump kept positions of word Q: lane handles bit 'lane'
#define DUMP_WORD(Q, BASE)                                                   \
  if (kept##Q & lbit) {                                                      \
    int r = (BASE) + (int)__popcll(kept##Q & lmask);                         \
    int p = c * CH + (Q) * 64 + lane;                                        \
    plist[cbuf][r] = p;                                                      \
    int o = out0 + r;                                                        \
    if (o < maxp) sel[o] = p;                                                \
  }

// 16-deep unconditional-clamped apply batch (16 loads in flight per thread)
#define APPLY16(OFS)                                                         \
  {                                                                          \
    int lim = pcn - 1;                                                       \
    int k0 = (OFS);                                                          \
    int a0 = k0, a1 = k0 + 1, a2 = k0 + 2, a3 = k0 + 3, a4 = k0 + 4,         \
        a5 = k0 + 5, a6 = k0 + 6, a7 = k0 + 7, a8 = k0 + 8, a9 = k0 + 9,     \
        aA = k0 + 10, aB = k0 + 11, aC = k0 + 12, aD = k0 + 13,              \
        aE = k0 + 14, aF = k0 + 15;                                          \
    int r0 = plist[pb][a0 < pcn ? a0 : lim];                                 \
    int r1 = plist[pb][a1 < pcn ? a1 : lim];                                 \
    int r2 = plist[pb][a2 < pcn ? a2 : lim];                                 \
    int r3 = plist[pb][a3 < pcn ? a3 : lim];                                 \
    int r4 = plist[pb][a4 < pcn ? a4 : lim];                                 \
    int r5 = plist[pb][a5 < pcn ? a5 : lim];                                 \
    int r6 = plist[pb][a6 < pcn ? a6 : lim];                                 \
    int r7 = plist[pb][a7 < pcn ? a7 : lim];                                 \
    int r8 = plist[pb][a8 < pcn ? a8 : lim];                                 \
    int r9 = plist[pb][a9 < pcn ? a9 : lim];                                 \
    int rA = plist[pb][aA < pcn ? aA : lim];                                 \
    int rB = plist[pb][aB < pcn ? aB : lim];                                 \
    int rC = plist[pb][aC < pcn ? aC : lim];                                 \
    int rD = plist[pb][aD < pcn ? aD : lim];                                 \
    int rE = plist[pb][aE < pcn ? aE : lim];                                 \
    int rF = plist[pb][aF < pcn ? aF : lim];                                 \
    u64 v0 = M[(size_t)r0 * nw + w], v1 = M[(size_t)r1 * nw + w];            \
    u64 v2 = M[(size_t)r2 * nw + w], v3 = M[(size_t)r3 * nw + w];            \
    u64 v4 = M[(size_t)r4 * nw + w], v5 = M[(size_t)r5 * nw + w];            \
    u64 v6 = M[(size_t)r6 * nw + w], v7 = M[(size_t)r7 * nw + w];            \
    u64 v8 = M[(size_t)r8 * nw + w], v9 = M[(size_t)r9 * nw + w];            \
    u64 vA = M[(size_t)rA * nw + w], vB = M[(size_t)rB * nw + w];            \
    u64 vC = M[(size_t)rC * nw + w], vD = M[(size_t)rD * nw + w];            \
    u64 vE = M[(size_t)rE * nw + w], vF = M[(size_t)rF * nw + w];            \
    acc |= v0;                                                               \
    acc |= (a1 < pcn) ? v1 : 0ULL;  acc |= (a2 < pcn) ? v2 : 0ULL;           \
    acc |= (a3 < pcn) ? v3 : 0ULL;  acc |= (a4 < pcn) ? v4 : 0ULL;           \
    acc |= (a5 < pcn) ? v5 : 0ULL;  acc |= (a6 < pcn) ? v6 : 0ULL;           \
    acc |= (a7 < pcn) ? v7 : 0ULL;  acc |= (a8 < pcn) ? v8 : 0ULL;           \
    acc |= (a9 < pcn) ? v9 : 0ULL;  acc |= (aA < pcn) ? vA : 0ULL;           \
    acc |= (aB < pcn) ? vB : 0ULL;  acc |= (aC < pcn) ? vC : 0ULL;           \
    acc |= (aD < pcn) ? vD : 0ULL;  acc |= (aE < pcn) ? vE : 0ULL;           \
    acc |= (aF < pcn) ? vF : 0ULL;                                           \
  }

// ---------------- K3: 512-wide chunked greedy scan (1 WG, 8 waves, 16 chunks) ----------------
// Per chunk: phase A (all 512 threads, 4 helpers/word) applies picks(c-1) to
// live[w >= c*CW]; barrier; phase B: wave 0 scans chunk c from 64 pinned
// registers (8 rows x 8 words per lane) while waves 4-7 prefetch chunk c+1's
// contiguous D tile; barrier.
__global__ __launch_bounds__(512, 1)
void k_scan(const u64* __restrict__ M, const u64* __restrict__ D,
            int n, int nw, int maxp,
            int* __restrict__ sel, int* __restrict__ cnt) {
  __shared__ u64 live[128];
  __shared__ u64 dbuf[2][CH][TP];
  __shared__ int plist[2][CH];
  __shared__ int pcnt[2];
  __shared__ int done_s;
  int t = threadIdx.x;           // 0..511
  int wave = t >> 6;
  int lane = t & 63;
  int nch = (nw + CW - 1) / CW;  // 16

  if (t < 128) {
    u64 v = ~0ULL;
    int base = t * 64;
    if (t >= nw || base >= n) v = 0ULL;
    else if (base + 64 > n) v = (1ULL << (n - base)) - 1ULL;
    live[t] = v;
  }
  if (t == 0) { pcnt[0] = 0; pcnt[1] = 0; done_s = 0; }
  {  // prologue: chunk-0 tile from D (contiguous, 64B/thread)
    const u64* src = D + (size_t)t * CW;
    bool rok = t < n;
#pragma unroll
    for (int q = 0; q < CW; ++q)
      dbuf[0][t][q] = (rok && q < nw) ? src[q] : 0ULL;
  }
  __syncthreads();

  int out = 0;

  for (int c = 0; c < nch; ++c) {
    int cbuf = c & 1;

    // ---- phase A: apply picks(c-1) to live[w >= c*CW] (4 helpers/word) ----
    if (c > 0) {
      int pb = (c - 1) & 1;
      int pcn = pcnt[pb];
      int w = t & 127;
      int h = t >> 7;                 // 0..3
      if (pcn > 0 && w >= c * CW && w < nw) {
        u64 acc = 0;
        for (int base = h * 16; base < pcn; base += 64) APPLY16(base)
        if (acc) atomicAnd(&live[w], ~acc);
      }
    }
    __syncthreads();

    // ---- phase B: wave 0 scans chunk c; waves 4-7 prefetch tile c+1 ----
    if (wave == 0) {
      LOADW(0) LOADW(1) LOADW(2) LOADW(3)
      LOADW(4) LOADW(5) LOADW(6) LOADW(7)

      u64 rem0 = sgpr64((c * CW + 0 < nw) ? live[c * CW + 0] : 0ULL);
      u64 rem1 = sgpr64((c * CW + 1 < nw) ? live[c * CW + 1] : 0ULL);
      u64 rem2 = sgpr64((c * CW + 2 < nw) ? live[c * CW + 2] : 0ULL);
      u64 rem3 = sgpr64((c * CW + 3 < nw) ? live[c * CW + 3] : 0ULL);
      u64 rem4 = sgpr64((c * CW + 4 < nw) ? live[c * CW + 4] : 0ULL);
      u64 rem5 = sgpr64((c * CW + 5 < nw) ? live[c * CW + 5] : 0ULL);
      u64 rem6 = sgpr64((c * CW + 6 < nw) ? live[c * CW + 6] : 0ULL);
      u64 rem7 = sgpr64((c * CW + 7 < nw) ? live[c * CW + 7] : 0ULL);

      u64 kept0 = 0, kept1 = 0, kept2 = 0, kept3 = 0;
      u64 kept4 = 0, kept5 = 0, kept6 = 0, kept7 = 0;
      int out0 = out;
      bool stop = false;

      SCAN_WORD(0) SCAN_WORD(1) SCAN_WORD(2) SCAN_WORD(3)
      SCAN_WORD(4) SCAN_WORD(5) SCAN_WORD(6) SCAN_WORD(7)

      int kc = out - out0;
      {
        int b1 = (int)__popcll(kept0);
        int b2 = b1 + (int)__popcll(kept1);
        int b3 = b2 + (int)__popcll(kept2);
        int b4 = b3 + (int)__popcll(kept3);
        int b5 = b4 + (int)__popcll(kept4);
        int b6 = b5 + (int)__popcll(kept5);
        int b7 = b6 + (int)__popcll(kept6);
        u64 lbit = (u64)1 << lane;
        u64 lmask = lbit - 1;
        DUMP_WORD(0, 0)
        DUMP_WORD(1, b1)
        DUMP_WORD(2, b2)
        DUMP_WORD(3, b3)
        DUMP_WORD(4, b4)
        DUMP_WORD(5, b5)
        DUMP_WORD(6, b6)
        DUMP_WORD(7, b7)
      }
      if (lane == 0) {
        pcnt[cbuf] = kc;
        if (stop) done_s = 1;
      }
    } else if (wave >= 4) {
      int c1 = c + 1;
      if (c1 < nch) {
        int rl = t - 256;                // 0..255 -> rows rl, rl+256
#pragma unroll
        for (int rr = 0; rr < 2; ++rr) {
          int r = rl + rr * 256;
          const u64* src = D + ((size_t)c1 * CH + r) * CW;
          bool rok = (c1 * CH + r) < n;
#pragma unroll
          for (int q = 0; q < CW; ++q)
            dbuf[c1 & 1][r][q] = (rok && c1 * CW + q < nw) ? src[q] : 0ULL;
        }
      }
    }
    __syncthreads();
    if (done_s) break;
  }
  if (t == 0) *cnt = (out < maxp) ? out : maxp;
}

// ---------------- K4: gather outputs ----------------
__global__ void k_emit(const float* __restrict__ preds,
                       const int* __restrict__ sidx,
                       const int* __restrict__ sel,
                       const int* __restrict__ cnt,
                       int maxp, float* __restrict__ out) {
  int k = blockIdx.x * blockDim.x + threadIdx.x;
  if (k >= maxp) return;
  int nk = *cnt;
  if (k < nk) {
    int p = sel[k];
    int orig = sidx[p];
#pragma unroll
    for (int q = 0; q < 5; ++q) out[k * 5 + q] = preds[orig * 5 + q];
    out[(size_t)maxp * 5 + k] = (float)orig;
  } else {
#pragma unroll
    for (int q = 0; q < 5; ++q) out[k * 5 + q] = 0.0f;
    out[(size_t)maxp * 5 + k] = -1.0f;
  }
}

extern "C" void kernel_launch(void* const* d_in, const int* in_sizes, int n_in,
                              void* d_out, int out_size, void* d_ws, size_t ws_size,
                              hipStream_t stream) {
  const float* preds = (const float*)d_in[0];
  const float* thr   = (const float*)d_in[1];
  float* out = (float*)d_out;
  int n    = in_sizes[0] / 5;          // 8192
  int maxp = out_size / 6;             // 1000
  int nw   = (n + 63) / 64;            // 128
  int nch  = (nw + CW - 1) / CW;       // 16
  int cpb  = 1024;
  int nyb  = (n + cpb - 1) / cpb;      // 8

  char* ws = (char*)d_ws;
  u64* M = (u64*)ws;
  size_t off = (size_t)n * nw * sizeof(u64);                   // 8 MB
  u64* D = (u64*)(ws + off);  off += (size_t)nch * CH * CW * sizeof(u64); // 512 KB
  float* sboxes = (float*)(ws + off);  off += (size_t)n * 4 * sizeof(float);
  int*   sidx   = (int*)(ws + off);    off += (size_t)n * sizeof(int);
  int*   sel    = (int*)(ws + off);    off += (size_t)maxp * sizeof(int);
  int*   cnt    = (int*)(ws + off);    off += sizeof(int) * 4;
  int*   pc     = (int*)(ws + off);    // nyb * n ints

  hipLaunchKernelGGL(k_rank_part, dim3((n + 255) / 256, nyb), dim3(256), 0,
                     stream, preds, n, cpb, pc);
  hipLaunchKernelGGL(k_scatter, dim3((n + 255) / 256), dim3(256), 0, stream,
                     preds, pc, n, nyb, sboxes, sidx);
  hipLaunchKernelGGL(k_mask, dim3(nw, nw), dim3(64), 0, stream,
                     sboxes, n, thr, M, D, nw);
  hipLaunchKernelGGL(k_scan, dim3(1), dim3(512), 0, stream,
                     M, D, n, nw, maxp, sel, cnt);
  hipLaunchKernelGGL(k_emit, dim3((maxp + 255) / 256), dim3(256), 0, stream,
                     preds, sidx, sel, cnt, maxp, out);
}

// Round 14
// 220.531 us; speedup vs baseline: 1.1401x; 1.1175x over previous
//
#include <hip/hip_runtime.h>

typedef unsigned long long u64;

// ---------------- K1a: partial rank counts (no atomics) ----------------
__global__ __launch_bounds__(256)
void k_rank_part(const float* __restrict__ preds, int n, int cpb,
                 int* __restrict__ pc) {
  __shared__ float cs[1024];
  int c0 = blockIdx.y * cpb;
  int cn = min(cpb, n - c0);
  for (int j = threadIdx.x; j < cn; j += blockDim.x)
    cs[j] = preds[(c0 + j) * 5 + 4];
  __syncthreads();
  int i = blockIdx.x * blockDim.x + threadIdx.x;
  if (i >= n) return;
  float ci = preds[i * 5 + 4];
  int cnt = 0;
  const float4* cs4 = (const float4*)cs;
  int cn4 = cn >> 2;
  for (int j4 = 0; j4 < cn4; ++j4) {
    float4 c4 = cs4[j4];
    int jb = c0 + j4 * 4;
    cnt += (c4.x > ci) || (c4.x == ci && (jb + 0) < i);
    cnt += (c4.y > ci) || (c4.y == ci && (jb + 1) < i);
    cnt += (c4.z > ci) || (c4.z == ci && (jb + 2) < i);
    cnt += (c4.w > ci) || (c4.w == ci && (jb + 3) < i);
  }
  for (int j = cn4 * 4; j < cn; ++j)
    cnt += (cs[j] > ci) || (cs[j] == ci && (c0 + j) < i);
  pc[(size_t)blockIdx.y * n + i] = cnt;
}

// ---------------- K1b: sum partials + scatter ----------------
__global__ __launch_bounds__(256)
void k_scatter(const float* __restrict__ preds, const int* __restrict__ pc,
               int n, int nyb, float* __restrict__ sboxes,
               int* __restrict__ sidx) {
  int i = blockIdx.x * blockDim.x + threadIdx.x;
  if (i >= n) return;
  int pos = 0;
  for (int y = 0; y < nyb; ++y) pos += pc[(size_t)y * n + i];
  sboxes[pos * 4 + 0] = preds[i * 5 + 0];
  sboxes[pos * 4 + 1] = preds[i * 5 + 1];
  sboxes[pos * 4 + 2] = preds[i * 5 + 2];
  sboxes[pos * 4 + 3] = preds[i * 5 + 3];
  sidx[pos] = i;
}

// ---------------- K2: suppression bitmask ----------------
// M[row*nw + w] row-major (upper triangle only; sub-diagonal words are
// garbage but only ever AND into already-consumed scan words).
// D2[row] = { M[row][crow], M[row][crow+1] } (crow = row>>6): the scan band.
__global__ void k_mask(const float* __restrict__ sboxes, int n,
                       const float* __restrict__ thr_p,
                       u64* __restrict__ M, u64* __restrict__ D2, int nw) {
  int wx = blockIdx.x;  // column word
  int ry = blockIdx.y;  // row group
  if (wx < ry) return;
  int lane = threadIdx.x;

  __shared__ float4 cb[64];
  __shared__ float cbar[64];
  const float4* sb4 = (const float4*)sboxes;
  int col0 = wx * 64;
  int cj = col0 + lane;
  int cjc = cj < n ? cj : n - 1;
  {
    float4 b4 = sb4[cjc];
    cb[lane] = b4;
    cbar[lane] = __fmul_rn(__fsub_rn(b4.z, b4.x), __fsub_rn(b4.w, b4.y));
  }
  __syncthreads();

  int row = ry * 64 + lane;
  if (row >= n) return;
  float th = *thr_p;
  float4 r4 = sb4[row];
  float rarea = __fmul_rn(__fsub_rn(r4.z, r4.x), __fsub_rn(r4.w, r4.y));

  u64 w = 0;
#pragma unroll 8
  for (int j = 0; j < 64; ++j) {
    float4 c4 = cb[j];
    float ix1 = fmaxf(r4.x, c4.x);
    float iy1 = fmaxf(r4.y, c4.y);
    float ix2 = fminf(r4.z, c4.z);
    float iy2 = fminf(r4.w, c4.w);
    float iw = fmaxf(__fsub_rn(ix2, ix1), 0.0f);
    float ih = fmaxf(__fsub_rn(iy2, iy1), 0.0f);
    float inter = __fmul_rn(iw, ih);
    float denom = __fadd_rn(__fsub_rn(__fadd_rn(rarea, cbar[j]), inter), 1e-12f);
    float iou = __fdiv_rn(inter, denom);
    int col = col0 + j;
    bool sup = (col > row) && (col < n) && (iou > th);
    w |= ((u64)sup) << j;
  }
  M[(size_t)row * nw + wx] = w;
  int q = wx - ry;                  // wave-uniform; ry == row>>6
  if (q == 0 || q == 1) D2[(size_t)row * 2 + q] = w;
}

// wave-uniform 64-bit broadcast from lane b (uniform) via v_readlane
__device__ __forceinline__ u64 bcast64(u64 v, int b) {
  unsigned lo = __builtin_amdgcn_readlane((unsigned)v, b);
  unsigned hi = __builtin_amdgcn_readlane((unsigned)(v >> 32), b);
  return ((u64)hi << 32) | lo;
}

// extract next set-bit row (uniform); safe when KX becomes 0 (dup row 0 of chunk)
#define EXTR1(RV, KX, c)                                                   \
  int RV = (c) * 64 + (KX ? (int)__builtin_ctzll(KX) : 0);                 \
  KX = KX ? (KX & (KX - 1)) : 0;

// consume pending buffer P (picks of chunk c-2) into live
#define CONSUME(P)                                                         \
  if (pc##P > 0) {                                                         \
    u64 a0 = 0, a1 = 0;                                                    \
    a0 |= (0 < pc##P) ? (p##P##0).x : 0; a1 |= (0 < pc##P) ? (p##P##0).y : 0; \
    a0 |= (1 < pc##P) ? (p##P##1).x : 0; a1 |= (1 < pc##P) ? (p##P##1).y : 0; \
    a0 |= (2 < pc##P) ? (p##P##2).x : 0; a1 |= (2 < pc##P) ? (p##P##2).y : 0; \
    a0 |= (3 < pc##P) ? (p##P##3).x : 0; a1 |= (3 < pc##P) ? (p##P##3).y : 0; \
    a0 |= (4 < pc##P) ? (p##P##4).x : 0; a1 |= (4 < pc##P) ? (p##P##4).y : 0; \
    a0 |= (5 < pc##P) ? (p##P##5).x : 0; a1 |= (5 < pc##P) ? (p##P##5).y : 0; \
    a0 |= (6 < pc##P) ? (p##P##6).x : 0; a1 |= (6 < pc##P) ? (p##P##6).y : 0; \
    a0 |= (7 < pc##P) ? (p##P##7).x : 0; a1 |= (7 < pc##P) ? (p##P##7).y : 0; \
    live0 &= ~a0; live1 &= ~a1; pc##P = 0;                                 \
  }

// issue this chunk's pick rows into pending buffer P (first 8);
// overflow picks (>8) are loaded and applied synchronously (rare path).
#define ISSUE_OV(P, c, K, kc)                                              \
  {                                                                        \
    u64 kx_ = (K);                                                         \
    EXTR1(R0_, kx_, c) EXTR1(R1_, kx_, c) EXTR1(R2_, kx_, c)               \
    EXTR1(R3_, kx_, c) EXTR1(R4_, kx_, c) EXTR1(R5_, kx_, c)               \
    EXTR1(R6_, kx_, c) EXTR1(R7_, kx_, c)                                  \
    pc##P = ((kc) < 8) ? (kc) : 8;                                         \
    p##P##0 = Mv[(size_t)R0_ * nw2 + lane];                                \
    p##P##1 = Mv[(size_t)R1_ * nw2 + lane];                                \
    p##P##2 = Mv[(size_t)R2_ * nw2 + lane];                                \
    p##P##3 = Mv[(size_t)R3_ * nw2 + lane];                                \
    p##P##4 = Mv[(size_t)R4_ * nw2 + lane];                                \
    p##P##5 = Mv[(size_t)R5_ * nw2 + lane];                                \
    p##P##6 = Mv[(size_t)R6_ * nw2 + lane];                                \
    p##P##7 = Mv[(size_t)R7_ * nw2 + lane];                                \
    int rc_ = (kc) - 8;                                                    \
    while (rc_ > 0) {                                                      \
      EXTR1(S0_, kx_, c) EXTR1(S1_, kx_, c) EXTR1(S2_, kx_, c)             \
      EXTR1(S3_, kx_, c) EXTR1(S4_, kx_, c) EXTR1(S5_, kx_, c)             \
      EXTR1(S6_, kx_, c) EXTR1(S7_, kx_, c)                                \
      ulonglong2 t0_ = Mv[(size_t)S0_ * nw2 + lane];                       \
      ulonglong2 t1_ = Mv[(size_t)S1_ * nw2 + lane];                       \
      ulonglong2 t2_ = Mv[(size_t)S2_ * nw2 + lane];                       \
      ulonglong2 t3_ = Mv[(size_t)S3_ * nw2 + lane];                       \
      ulonglong2 t4_ = Mv[(size_t)S4_ * nw2 + lane];                       \
      ulonglong2 t5_ = Mv[(size_t)S5_ * nw2 + lane];                       \
      ulonglong2 t6_ = Mv[(size_t)S6_ * nw2 + lane];                       \
      ulonglong2 t7_ = Mv[(size_t)S7_ * nw2 + lane];                       \
      u64 a0_ = 0, a1_ = 0;                                                \
      a0_ |= (0 < rc_) ? t0_.x : 0; a1_ |= (0 < rc_) ? t0_.y : 0;          \
      a0_ |= (1 < rc_) ? t1_.x : 0; a1_ |= (1 < rc_) ? t1_.y : 0;          \
      a0_ |= (2 < rc_) ? t2_.x : 0; a1_ |= (2 < rc_) ? t2_.y : 0;          \
      a0_ |= (3 < rc_) ? t3_.x : 0; a1_ |= (3 < rc_) ? t3_.y : 0;          \
      a0_ |= (4 < rc_) ? t4_.x : 0; a1_ |= (4 < rc_) ? t4_.y : 0;          \
      a0_ |= (5 < rc_) ? t5_.x : 0; a1_ |= (5 < rc_) ? t5_.y : 0;          \
      a0_ |= (6 < rc_) ? t6_.x : 0; a1_ |= (6 < rc_) ? t6_.y : 0;          \
      a0_ |= (7 < rc_) ? t7_.x : 0; a1_ |= (7 < rc_) ? t7_.y : 0;          \
      live0 &= ~a0_; live1 &= ~a1_;                                        \
      rc_ -= 8;                                                            \
    }                                                                      \
  }

// one 64-box chunk: consume pending(c-2); rem = live-word & carry(c-1);
// register-only serial scan via band readlanes; write sel; issue pick rows;
// prefetch band(c+4).
#define CHUNK(c, BLO, BHI, P)                                              \
  if (out < maxp && (c) < nch) {                                           \
    CONSUME(P)                                                             \
    u64 lw_ = ((c) & 1) ? live1 : live0;                                   \
    u64 rem_ = bcast64(lw_, (c) >> 1) & carry;                             \
    u64 K_ = 0, cn_ = ~0ULL;                                               \
    int left_ = maxp - out, c2_ = 0;                                       \
    while (rem_) {                                                         \
      int b_ = (int)__builtin_ctzll(rem_);                                 \
      K_ |= (u64)1 << b_;                                                  \
      ++c2_;                                                               \
      if (c2_ >= left_) break;                                             \
      u64 sc_ = bcast64(BLO, b_), sn_ = bcast64(BHI, b_);                  \
      rem_ &= rem_ - 1; rem_ &= ~sc_; cn_ &= ~sn_;                         \
    }                                                                      \
    carry = cn_;                                                           \
    int kc_ = (int)__popcll(K_);                                           \
    if ((K_ >> lane) & 1) {                                                \
      int pos_ = out + (int)__popcll(K_ & (((u64)1 << lane) - 1));         \
      if (pos_ < maxp) sel[pos_] = (c) * 64 + lane;                        \
    }                                                                      \
    out += kc_;                                                            \
    if (out < maxp && kc_ > 0) ISSUE_OV(P, c, K_, kc_)                     \
    {                                                                      \
      int cc_ = (c) + 4;                                                   \
      if (cc_ < nch) {                                                     \
        ulonglong2 v_ = D2v[(size_t)cc_ * 64 + lane];                      \
        BLO = v_.x; BHI = v_.y;                                            \
      }                                                                    \
    }                                                                      \
  }

// ---------------- K3: single-wave, barrier-free greedy scan ----------------
__global__ void k_scan(const u64* __restrict__ M, const u64* __restrict__ D2,
                       int n, int nw, int maxp,
                       int* __restrict__ sel, int* __restrict__ cnt) {
  int lane = threadIdx.x;       // 0..63 (one wave)
  int nch = nw;                 // one 64-bit word (64 boxes) per chunk
  int nw2 = nw >> 1;
  const ulonglong2* Mv = (const ulonglong2*)M;
  const ulonglong2* D2v = (const ulonglong2*)D2;

  // live words 2*lane and 2*lane+1
  u64 live0, live1;
  {
    int w0 = 2 * lane, w1 = 2 * lane + 1;
    u64 m0 = 0, m1 = 0;
    if (w0 < nw) {
      long long hi = (long long)(w0 + 1) * 64;
      m0 = (hi <= n) ? ~0ULL
                     : ((n > (long long)w0 * 64)
                            ? (((u64)1 << (n - w0 * 64)) - 1) : 0ULL);
    }
    if (w1 < nw) {
      long long hi = (long long)(w1 + 1) * 64;
      m1 = (hi <= n) ? ~0ULL
                     : ((n > (long long)w1 * 64)
                            ? (((u64)1 << (n - w1 * 64)) - 1) : 0ULL);
    }
    live0 = m0; live1 = m1;
  }

  // band ring (chunks c..c+3), per-lane row c*64+lane's words {c, c+1}
  u64 b0lo = 0, b0hi = 0, b1lo = 0, b1hi = 0;
  u64 b2lo = 0, b2hi = 0, b3lo = 0, b3hi = 0;
  {
    if (0 < nch) { ulonglong2 v = D2v[(size_t)0 * 64 + lane]; b0lo = v.x; b0hi = v.y; }
    if (1 < nch) { ulonglong2 v = D2v[(size_t)1 * 64 + lane]; b1lo = v.x; b1hi = v.y; }
    if (2 < nch) { ulonglong2 v = D2v[(size_t)2 * 64 + lane]; b2lo = v.x; b2hi = v.y; }
    if (3 < nch) { ulonglong2 v = D2v[(size_t)3 * 64 + lane]; b3lo = v.x; b3hi = v.y; }
  }

  // pending row buffers (picks of chunk c applied at c+2)
  ulonglong2 pA0 = {0, 0}, pA1 = {0, 0}, pA2 = {0, 0}, pA3 = {0, 0};
  ulonglong2 pA4 = {0, 0}, pA5 = {0, 0}, pA6 = {0, 0}, pA7 = {0, 0};
  ulonglong2 pB0 = {0, 0}, pB1 = {0, 0}, pB2 = {0, 0}, pB3 = {0, 0};
  ulonglong2 pB4 = {0, 0}, pB5 = {0, 0}, pB6 = {0, 0}, pB7 = {0, 0};
  int pcA = 0, pcB = 0;

  int out = 0;
  u64 carry = ~0ULL;

  for (int kk = 0; kk < nch && out < maxp; kk += 4) {
    CHUNK(kk + 0, b0lo, b0hi, A)
    CHUNK(kk + 1, b1lo, b1hi, B)
    CHUNK(kk + 2, b2lo, b2hi, A)
    CHUNK(kk + 3, b3lo, b3hi, B)
  }
  if (lane == 0) *cnt = (out < maxp) ? out : maxp;
}

// ---------------- K4: gather outputs ----------------
__global__ void k_emit(const float* __restrict__ preds,
                       const int* __restrict__ sidx,
                       const int* __restrict__ sel,
                       const int* __restrict__ cnt,
                       int maxp, float* __restrict__ out) {
  int k = blockIdx.x * blockDim.x + threadIdx.x;
  if (k >= maxp) return;
  int nk = *cnt;
  if (k < nk) {
    int p = sel[k];
    int orig = sidx[p];
#pragma unroll
    for (int q = 0; q < 5; ++q) out[k * 5 + q] = preds[orig * 5 + q];
    out[(size_t)maxp * 5 + k] = (float)orig;
  } else {
#pragma unroll
    for (int q = 0; q < 5; ++q) out[k * 5 + q] = 0.0f;
    out[(size_t)maxp * 5 + k] = -1.0f;
  }
}

extern "C" void kernel_launch(void* const* d_in, const int* in_sizes, int n_in,
                              void* d_out, int out_size, void* d_ws, size_t ws_size,
                              hipStream_t stream) {
  const float* preds = (const float*)d_in[0];
  const float* thr   = (const float*)d_in[1];
  float* out = (float*)d_out;
  int n    = in_sizes[0] / 5;          // 8192
  int maxp = out_size / 6;             // 1000
  int nw   = (n + 63) / 64;            // 128
  int cpb  = 1024;
  int nyb  = (n + cpb - 1) / cpb;      // 8

  char* ws = (char*)d_ws;
  u64* M = (u64*)ws;
  size_t off = (size_t)n * nw * sizeof(u64);                   // 8 MB
  u64* D2 = (u64*)(ws + off);  off += (size_t)n * 2 * sizeof(u64);  // 128 KB
  float* sboxes = (float*)(ws + off);  off += (size_t)n * 4 * sizeof(float);
  int*   sidx   = (int*)(ws + off);    off += (size_t)n * sizeof(int);
  int*   sel    = (int*)(ws + off);    off += (size_t)maxp * sizeof(int);
  int*   cnt    = (int*)(ws + off);    off += sizeof(int) * 4;
  int*   pc     = (int*)(ws + off);    // nyb * n ints

  hipLaunchKernelGGL(k_rank_part, dim3((n + 255) / 256, nyb), dim3(256), 0,
                     stream, preds, n, cpb, pc);
  hipLaunchKernelGGL(k_scatter, dim3((n + 255) / 256), dim3(256), 0, stream,
                     preds, pc, n, nyb, sboxes, sidx);
  hipLaunchKernelGGL(k_mask, dim3(nw, nw), dim3(64), 0, stream,
                     sboxes, n, thr, M, D2, nw);
  hipLaunchKernelGGL(k_scan, dim3(1), dim3(64), 0, stream,
                     M, D2, n, nw, maxp, sel, cnt);
  hipLaunchKernelGGL(k_emit, dim3((maxp + 255) / 256), dim3(256), 0, stream,
                     preds, sidx, sel, cnt, maxp, out);
}